// Round 2
// baseline (192.145 us; speedup 1.0000x reference)
//
#include <hip/hip_runtime.h>

// Problem constants (fixed by the reference).
#define D      256        // vq_embed_dim == C
#define N_E    16384      // codebook size
#define NPTS   8192       // B*H*W
#define ZOUT   2097152    // elements of z_hat_out
#define MARGIN 2.0e-2f    // candidate window; bf16-hi GEMM d-error ~7 sigma
#define STRIPS 4          // 256-code strips per block

typedef short bf16x8 __attribute__((ext_vector_type(8)));
typedef unsigned short us8 __attribute__((ext_vector_type(8)));
typedef float f32x16 __attribute__((ext_vector_type(16)));
typedef unsigned long long u64;

__device__ __forceinline__ unsigned short f2bf(float x) {  // RNE
    unsigned int u = __float_as_uint(x);
    return (unsigned short)((u + 0x7FFFu + ((u >> 16) & 1u)) >> 16);
}
__device__ __forceinline__ float bf2f(unsigned short h) {
    return __uint_as_float((unsigned int)h << 16);
}
__device__ __forceinline__ void gl_lds16(const void* g, void* l) {
    __builtin_amdgcn_global_load_lds(
        (const __attribute__((address_space(1))) unsigned int*)g,
        (__attribute__((address_space(3))) unsigned int*)l, 16, 0, 0);
}

// ---------------------------------------------------------------------------
// Fused prep. Blocks [0,256): z (32 points each). Blocks [256,768): emb
// (32 codes each). Zpk = bf16(-2z), Epk = bf16(emb), both in MFMA fragment-
// chunk layout (chunk (g,ks): 64 lanes x 16B, lane l = (row&31)+((k>>3)&1)*32).
// Zf32 = z transposed to [n][k]. e2[j] = |emb_j|^2 fp32.
// E2pk[g]: A-fragment encoding e2 as bf16 hi/lo pair in k-slots 0/1 (lanes
// 32-63 zero) so the GEMM can fold +e2 with one extra MFMA per acc tile.
// ---------------------------------------------------------------------------
__global__ __launch_bounds__(256) void prep(
    const float* __restrict__ z, const float* __restrict__ emb,
    unsigned short* __restrict__ Zpk, float* __restrict__ Zf32,
    unsigned short* __restrict__ Epk, float* __restrict__ e2,
    unsigned short* __restrict__ E2pk) {
    __shared__ float sh[32];
    const int t = threadIdx.x;
    if (blockIdx.x < 256) {
        const int n0 = blockIdx.x * 32;
        const int p = t & 31, ks8 = t >> 5;     // 8 k-slabs of 32
        const int n = n0 + p;
        const int b = n >> 10, hw = n & 1023;
        const float* zb = z + (size_t)b * 262144 + hw;
        const int k0 = ks8 * 32;
        float v[32];
        #pragma unroll
        for (int kk = 0; kk < 32; ++kk)
            v[kk] = zb[(size_t)(k0 + kk) * 1024];   // coalesced in p
        #pragma unroll
        for (int i = 0; i < 8; ++i) {
            float4 f = {v[i * 4], v[i * 4 + 1], v[i * 4 + 2], v[i * 4 + 3]};
            *(float4*)(Zf32 + (size_t)n * D + k0 + i * 4) = f;
        }
        const int g = n >> 5;
        #pragma unroll
        for (int i = 0; i < 4; ++i) {               // 4 us8 per 32-k slab
            us8 hv;
            #pragma unroll
            for (int c = 0; c < 8; ++c) hv[c] = f2bf(-2.0f * v[i * 8 + c]);
            const int kabs = k0 + i * 8;
            const int ks = kabs >> 4;
            const int l = (n & 31) + ((kabs >> 3) & 1) * 32;
            *(us8*)(Zpk + ((size_t)(g * 16 + ks) * 64 + l) * 8) = hv;
        }
    } else {
        const int j0 = (blockIdx.x - 256) * 32;
        const int jj = j0 + (t >> 3), q = t & 7;    // 8 k-slabs of 32
        const float* row = emb + (size_t)jj * D + q * 32;
        float v[32];
        float s = 0.f;
        #pragma unroll
        for (int i = 0; i < 8; ++i) {
            const float4 x = *(const float4*)(row + i * 4);
            v[i * 4] = x.x; v[i * 4 + 1] = x.y; v[i * 4 + 2] = x.z; v[i * 4 + 3] = x.w;
            s += x.x * x.x + x.y * x.y + x.z * x.z + x.w * x.w;
        }
        const int g = jj >> 5;
        #pragma unroll
        for (int i = 0; i < 4; ++i) {
            us8 hv;
            #pragma unroll
            for (int c = 0; c < 8; ++c) hv[c] = f2bf(v[i * 8 + c]);
            const int kabs = q * 32 + i * 8;
            const int ks = kabs >> 4;
            const int l = (jj & 31) + ((kabs >> 3) & 1) * 32;
            *(us8*)(Epk + ((size_t)(g * 16 + ks) * 64 + l) * 8) = hv;
        }
        s += __shfl_xor(s, 1);
        s += __shfl_xor(s, 2);
        s += __shfl_xor(s, 4);
        if (q == 0) { e2[jj] = s; sh[t >> 3] = s; }
        __syncthreads();
        if (t < 64) {
            us8 hv;
            #pragma unroll
            for (int c = 0; c < 8; ++c) hv[c] = 0;
            if (t < 32) {
                const float vv = sh[t];
                const unsigned short hi = f2bf(vv);
                hv[0] = hi;
                hv[1] = f2bf(vv - bf2f(hi));
            }
            *(us8*)(E2pk + (size_t)(blockIdx.x - 256) * 512 + t * 8) = hv;
        }
    }
}

// ---------------------------------------------------------------------------
// GEMM + group-min + cluster candidate mask. Block: 128 points (LDS, staged
// once) x STRIPS*256 codes. 4 waves; wave wid owns a DISTINCT 64-code column,
// all 128 points. Wave frags: 2 code x 4 point of 32x32x16; ef from global
// (fragment-contiguous chunks, depth-2 prefetch), pf from LDS (depth-2).
// e2 is folded into the accumulator by one extra MFMA per tile (A = E2pk
// hi/lo fragment, B = constant unit fragment) so d~ = acc directly.
// Per (point, 64-code group) emits:
//   tminv = min over 64 codes
//   tmask = 16-bit mask: bit b set iff min over codes [4b,4b+4) <= min+MARGIN
// (superset of the per-code candidate set -> coverage preserved).
// ---------------------------------------------------------------------------
__global__ __launch_bounds__(256, 2) void mfma_gemm(
    const unsigned short* __restrict__ Epk, const unsigned short* __restrict__ Zpk,
    const unsigned short* __restrict__ E2pk, float* __restrict__ tminv,
    unsigned short* __restrict__ tmask) {
    __shared__ unsigned short Zbuf[64 * 512];   // 64 KB

    const int tid = threadIdx.x, lane = tid & 63, wid = tid >> 6;
    const int c32 = lane & 31, l5 = lane >> 5;
    const int n0 = blockIdx.x * 128;
    const int cs0 = blockIdx.y * (STRIPS * 256);

    // Unit B fragment: B[point, k]=1 for k-slots 0,1 of the fold chunk.
    us8 puu;
    #pragma unroll
    for (int c = 0; c < 8; ++c) puu[c] = 0;
    if (l5 == 0) { puu[0] = 0x3F80; puu[1] = 0x3F80; }
    const bf16x8 pu = (bf16x8)puu;

    #pragma unroll
    for (int ks = 0; ks < 16; ++ks)
        gl_lds16(Zpk + ((size_t)((n0 >> 5) + wid) * 16 + ks) * 512 + lane * 8,
                 Zbuf + (wid * 16 + ks) * 512);
    __syncthreads();   // single drain per block

    for (int s = 0; s < STRIPS; ++s) {
        const int cb = cs0 + s * 256 + wid * 64;   // this wave's 64 codes
        const unsigned short* eb = Epk + ((size_t)(cb >> 5) * 16) * 512 + lane * 8;
        const unsigned short* zb = Zbuf + lane * 8;

        // e2 fold fragments (consumed after the K loop; latency fully hidden)
        const bf16x8 e2f0 = *(const bf16x8*)(E2pk + (size_t)(cb >> 5) * 512 + lane * 8);
        const bf16x8 e2f1 = *(const bf16x8*)(E2pk + ((size_t)(cb >> 5) + 1) * 512 + lane * 8);

        f32x16 acc[2][4];
        const f32x16 z16 = {0.f};
        #pragma unroll
        for (int i = 0; i < 2; ++i)
            #pragma unroll
            for (int j = 0; j < 4; ++j) acc[i][j] = z16;

        // depth-2 prefetch, parity-rotated register buffers
        bf16x8 eq[2][2], pq[2][4];
        #pragma unroll
        for (int par = 0; par < 2; ++par) {
            eq[par][0] = *(const bf16x8*)(eb + par * 512);
            eq[par][1] = *(const bf16x8*)(eb + (16 + par) * 512);
            #pragma unroll
            for (int j = 0; j < 4; ++j)
                pq[par][j] = *(const bf16x8*)(zb + (j * 16 + par) * 512);
        }

        #pragma unroll 4
        for (int ks = 0; ks < 16; ++ks) {
            const int p = ks & 1;
            const bf16x8 ec0 = eq[p][0], ec1 = eq[p][1];
            const bf16x8 pc0 = pq[p][0], pc1 = pq[p][1];
            const bf16x8 pc2 = pq[p][2], pc3 = pq[p][3];
            if (ks < 14) {
                eq[p][0] = *(const bf16x8*)(eb + (ks + 2) * 512);
                eq[p][1] = *(const bf16x8*)(eb + (16 + ks + 2) * 512);
                #pragma unroll
                for (int j = 0; j < 4; ++j)
                    pq[p][j] = *(const bf16x8*)(zb + (j * 16 + ks + 2) * 512);
            }
            acc[0][0] = __builtin_amdgcn_mfma_f32_32x32x16_bf16(ec0, pc0, acc[0][0], 0, 0, 0);
            acc[0][1] = __builtin_amdgcn_mfma_f32_32x32x16_bf16(ec0, pc1, acc[0][1], 0, 0, 0);
            acc[0][2] = __builtin_amdgcn_mfma_f32_32x32x16_bf16(ec0, pc2, acc[0][2], 0, 0, 0);
            acc[0][3] = __builtin_amdgcn_mfma_f32_32x32x16_bf16(ec0, pc3, acc[0][3], 0, 0, 0);
            acc[1][0] = __builtin_amdgcn_mfma_f32_32x32x16_bf16(ec1, pc0, acc[1][0], 0, 0, 0);
            acc[1][1] = __builtin_amdgcn_mfma_f32_32x32x16_bf16(ec1, pc1, acc[1][1], 0, 0, 0);
            acc[1][2] = __builtin_amdgcn_mfma_f32_32x32x16_bf16(ec1, pc2, acc[1][2], 0, 0, 0);
            acc[1][3] = __builtin_amdgcn_mfma_f32_32x32x16_bf16(ec1, pc3, acc[1][3], 0, 0, 0);
        }
        // fold +e2[code] into every accumulator tile
        #pragma unroll
        for (int j = 0; j < 4; ++j) {
            acc[0][j] = __builtin_amdgcn_mfma_f32_32x32x16_bf16(e2f0, pu, acc[0][j], 0, 0, 0);
            acc[1][j] = __builtin_amdgcn_mfma_f32_32x32x16_bf16(e2f1, pu, acc[1][j], 0, 0, 0);
        }

        // Epilogue: cluster-of-4 mins -> group min + 16-bit cluster mask.
        // Cluster (rows 8q+4*l5 .. +3 of 32-block i) lives in regs 4q..4q+3.
        #pragma unroll
        for (int j = 0; j < 4; ++j) {
            float cm[2][4];
            #pragma unroll
            for (int i = 0; i < 2; ++i)
                #pragma unroll
                for (int q = 0; q < 4; ++q) {
                    float t0 = fminf(acc[i][j][q * 4], acc[i][j][q * 4 + 1]);
                    t0 = fminf(t0, acc[i][j][q * 4 + 2]);
                    cm[i][q] = fminf(t0, acc[i][j][q * 4 + 3]);
                }
            float m = fminf(cm[0][0], cm[0][1]);
            m = fminf(m, cm[0][2]); m = fminf(m, cm[0][3]);
            m = fminf(m, cm[1][0]); m = fminf(m, cm[1][1]);
            m = fminf(m, cm[1][2]); m = fminf(m, cm[1][3]);
            m = fminf(m, __shfl_xor(m, 32));   // fold the two l5 halves
            const float th = m + MARGIN;
            unsigned mm = 0;
            #pragma unroll
            for (int i = 0; i < 2; ++i)
                #pragma unroll
                for (int q = 0; q < 4; ++q)
                    mm |= (cm[i][q] <= th) ? (1u << (i * 8 + 2 * q)) : 0u;
            mm <<= l5;                          // this half's bits sit at +l5
            mm |= (unsigned)__shfl_xor((int)mm, 32);
            if (l5 == 0) {
                const size_t pt = (size_t)(n0 + j * 32 + c32);
                tminv[pt * 256 + (cb >> 6)] = m;
                tmask[pt * 256 + (cb >> 6)] = (unsigned short)mm;
            }
        }
    }
}

// ---------------------------------------------------------------------------
// Rescore: m1 = min over 256 group-mins; for groups with gmin <= m1 + MARGIN,
// read the 16-bit cluster mask and exact-fp32 rescore the 4 codes of each set
// cluster: wave splits into 4 quarters, quarter qr dots row (c0+qr) against
// its private z-slice registers, 4-step butterfly + cross-quarter key fold.
// Tie -> lowest j. Emits idxf + total_idx. Zeroes loss.
// ---------------------------------------------------------------------------
__global__ __launch_bounds__(256) void rescore(
    const float* __restrict__ tminv, const unsigned short* __restrict__ tmask,
    const float* __restrict__ Zf32, const float* __restrict__ emb,
    const float* __restrict__ e2, int* __restrict__ idxf,
    float* __restrict__ out_idx, float* __restrict__ loss) {
    const int tid = threadIdx.x, lane = tid & 63, w = tid >> 6;
    const int n = blockIdx.x * 4 + w;
    if (blockIdx.x == 0 && tid == 0) loss[0] = 0.f;

    const int sl = lane & 15, qr = lane >> 4;
    float4 zs[4];   // this lane's z slice: k = p*64 + sl*4 .. +3
    #pragma unroll
    for (int p = 0; p < 4; ++p)
        zs[p] = *(const float4*)(Zf32 + (size_t)n * D + p * 64 + sl * 4);

    const float4 tv = *(const float4*)(tminv + (size_t)n * 256 + lane * 4);
    float m1 = fminf(fminf(tv.x, tv.y), fminf(tv.z, tv.w));
    #pragma unroll
    for (int st = 1; st < 64; st <<= 1) m1 = fminf(m1, __shfl_xor(m1, st));
    const float thresh = m1 + MARGIN;

    u64 best = ~0ull;
    const float tva[4] = {tv.x, tv.y, tv.z, tv.w};
    #pragma unroll
    for (int k = 0; k < 4; ++k) {
        u64 gm = __ballot(tva[k] <= thresh);
        while (gm) {
            const int bit = (int)__builtin_ctzll(gm);
            gm &= gm - 1;
            const int g = bit * 4 + k;                 // 64-code group id
            unsigned cm = tmask[(size_t)n * 256 + g];  // uniform broadcast
            while (cm) {
                const int cl = (int)__builtin_ctz(cm);
                cm &= cm - 1;
                const int c0 = g * 64 + cl * 4;        // cluster base code
                const int c = c0 + qr;                 // this quarter's row
                const float* er = emb + (size_t)c * D;
                float sacc = 0.f;
                #pragma unroll
                for (int p = 0; p < 4; ++p) {
                    const float4 ev = *(const float4*)(er + p * 64 + sl * 4);
                    sacc += ev.x * zs[p].x + ev.y * zs[p].y +
                            ev.z * zs[p].z + ev.w * zs[p].w;
                }
                sacc += __shfl_xor(sacc, 1);
                sacc += __shfl_xor(sacc, 2);
                sacc += __shfl_xor(sacc, 4);
                sacc += __shfl_xor(sacc, 8);
                const float d = e2[c] - 2.0f * sacc;
                unsigned int u = __float_as_uint(d);
                u = (u & 0x80000000u) ? ~u : (u | 0x80000000u);
                u64 key = ((u64)u << 32) | (unsigned int)c;
                u64 o = __shfl_xor(key, 16); if (o < key) key = o;
                o = __shfl_xor(key, 32); if (o < key) key = o;
                if (key < best) best = key;            // same on all lanes
            }
        }
    }
    if (lane == 0) {
        const int bi = (int)(unsigned int)(best & 0xFFFFFFFFull);
        idxf[n] = bi;
        const int b = n >> 10, hw = n & 1023;
        const float fv = (float)bi;
        #pragma unroll
        for (int sc = 0; sc < 4; ++sc) out_idx[b * 4096 + sc * 1024 + hw] = fv;
    }
}

// ---------------------------------------------------------------------------
// Gather q = emb[idx]; z_hat_out = z + (4q - z); loss accumulation.
// 1024 blocks: (4 c-tiles of 64) x (8 b x 32 hw-tiles). 256 thr = 32 hw x 8 cg.
// ---------------------------------------------------------------------------
__global__ __launch_bounds__(256) void quant_loss(
    const float* __restrict__ z, const float* __restrict__ emb,
    const int* __restrict__ idxf, float* __restrict__ out,
    float* __restrict__ loss) {
    __shared__ int idx_l[32];
    __shared__ float wsum[4];
    const int blk = blockIdx.x;
    const int c0 = (blk >> 8) * 64;
    const int rem = blk & 255;
    const int b = rem >> 5, hw0 = (rem & 31) * 32;
    const int t = threadIdx.x, hw_l = t & 31, cg = t >> 5;
    if (t < 32) idx_l[t] = idxf[b * 1024 + hw0 + t];
    __syncthreads();
    const int j = idx_l[hw_l];
    const float* er = emb + (size_t)j * D + c0 + cg * 8;
    const float4 q0 = *(const float4*)er;
    const float4 q1 = *(const float4*)(er + 4);
    const float qv[8] = {q0.x, q0.y, q0.z, q0.w, q1.x, q1.y, q1.z, q1.w};
    float e = 0.f;
    #pragma unroll
    for (int cc = 0; cc < 8; ++cc) {
        const int c = c0 + cg * 8 + cc;
        const size_t zi = (size_t)b * 262144 + (size_t)c * 1024 + hw0 + hw_l;
        const float zv = z[zi];
        const float q = qv[cc];
        const float zh = ((q + q) + q) + q;   // mimic 4-step accumulation
        out[zi] = zv + (zh - zv);
        e += 30.0f * q * q - 20.0f * q * zv + 4.0f * zv * zv;
    }
    #pragma unroll
    for (int off = 32; off > 0; off >>= 1) e += __shfl_down(e, off);
    if ((t & 63) == 0) wsum[t >> 6] = e;
    __syncthreads();
    if (t == 0) {
        const float s = wsum[0] + wsum[1] + wsum[2] + wsum[3];
        atomicAdd(loss, s * (0.3125f / 2097152.0f));
    }
}

// ---------------------------------------------------------------------------
extern "C" void kernel_launch(void* const* d_in, const int* in_sizes, int n_in,
                              void* d_out, int out_size, void* d_ws, size_t ws_size,
                              hipStream_t stream) {
    const float* z = (const float*)d_in[0];     // [8,256,32,32]
    const float* emb = (const float*)d_in[1];   // [16384,256]
    float* out = (float*)d_out;                 // z_hat_out | loss | total_idx

    // Workspace (~32.6 MB)
    unsigned short* Zpk = (unsigned short*)d_ws;            // 8192*256 bf16
    unsigned short* Epk = Zpk + (size_t)NPTS * D;           // 16384*256 bf16
    float* Zf32 = (float*)(Epk + (size_t)N_E * D);          // 8192*256 f32
    float* e2 = Zf32 + (size_t)NPTS * D;                    // 16384 f32
    float* tminv = e2 + N_E;                                // 8192*256 f32
    unsigned short* tmask = (unsigned short*)(tminv + (size_t)NPTS * 256); // 8192*256 u16
    unsigned short* E2pk = tmask + (size_t)NPTS * 256;      // 512*512 bf16
    int* idxf = (int*)(E2pk + (size_t)512 * 512);           // 8192 i32

    float* loss = out + ZOUT;
    float* out_idx = out + ZOUT + 1;

    prep<<<768, 256, 0, stream>>>(z, emb, Zpk, Zf32, Epk, e2, E2pk);
    mfma_gemm<<<dim3(NPTS / 128, N_E / (256 * STRIPS)), 256, 0, stream>>>(
        Epk, Zpk, E2pk, tminv, tmask);
    rescore<<<NPTS / 4, 256, 0, stream>>>(tminv, tmask, Zf32, emb, e2, idxf,
                                          out_idx, loss);
    quant_loss<<<1024, 256, 0, stream>>>(z, emb, idxf, out, loss);
}

// Round 3
// 182.536 us; speedup vs baseline: 1.0526x; 1.0526x over previous
//
#include <hip/hip_runtime.h>

// Problem constants (fixed by the reference).
#define D      256        // vq_embed_dim == C
#define N_E    16384      // codebook size
#define NPTS   8192       // B*H*W
#define ZOUT   2097152    // elements of z_hat_out
#define MARGIN 2.0e-2f    // candidate window; bf16-hi GEMM d-error ~7 sigma
#define STRIPS 4          // 256-code strips per block

typedef short bf16x8 __attribute__((ext_vector_type(8)));
typedef unsigned short us8 __attribute__((ext_vector_type(8)));
typedef float f32x16 __attribute__((ext_vector_type(16)));
typedef unsigned long long u64;

__device__ __forceinline__ unsigned short f2bf(float x) {  // RNE
    unsigned int u = __float_as_uint(x);
    return (unsigned short)((u + 0x7FFFu + ((u >> 16) & 1u)) >> 16);
}
__device__ __forceinline__ void gl_lds16(const void* g, void* l) {
    __builtin_amdgcn_global_load_lds(
        (const __attribute__((address_space(1))) unsigned int*)g,
        (__attribute__((address_space(3))) unsigned int*)l, 16, 0, 0);
}

// ---------------------------------------------------------------------------
// Fused prep. Blocks [0,256): z (32 points each). Blocks [256,768): emb
// (32 codes each). Zpk = bf16(-2z), Epk = bf16(emb), both in MFMA fragment-
// chunk layout (chunk (g,ks): 64 lanes x 16B, lane l = (row&31)+((k>>3)&1)*32).
// Zf32 = z transposed to [n][k]. e2[j] = |emb_j|^2 fp32.
// ---------------------------------------------------------------------------
__global__ __launch_bounds__(256) void prep(
    const float* __restrict__ z, const float* __restrict__ emb,
    unsigned short* __restrict__ Zpk, float* __restrict__ Zf32,
    unsigned short* __restrict__ Epk, float* __restrict__ e2) {
    const int t = threadIdx.x;
    if (blockIdx.x < 256) {
        const int n0 = blockIdx.x * 32;
        const int p = t & 31, ks8 = t >> 5;     // 8 k-slabs of 32
        const int n = n0 + p;
        const int b = n >> 10, hw = n & 1023;
        const float* zb = z + (size_t)b * 262144 + hw;
        const int k0 = ks8 * 32;
        float v[32];
        #pragma unroll
        for (int kk = 0; kk < 32; ++kk)
            v[kk] = zb[(size_t)(k0 + kk) * 1024];   // coalesced in p
        #pragma unroll
        for (int i = 0; i < 8; ++i) {
            float4 f = {v[i * 4], v[i * 4 + 1], v[i * 4 + 2], v[i * 4 + 3]};
            *(float4*)(Zf32 + (size_t)n * D + k0 + i * 4) = f;
        }
        const int g = n >> 5;
        #pragma unroll
        for (int i = 0; i < 4; ++i) {               // 4 us8 per 32-k slab
            us8 hv;
            #pragma unroll
            for (int c = 0; c < 8; ++c) hv[c] = f2bf(-2.0f * v[i * 8 + c]);
            const int kabs = k0 + i * 8;
            const int ks = kabs >> 4;
            const int l = (n & 31) + ((kabs >> 3) & 1) * 32;
            *(us8*)(Zpk + ((size_t)(g * 16 + ks) * 64 + l) * 8) = hv;
        }
    } else {
        const int j0 = (blockIdx.x - 256) * 32;
        const int jj = j0 + (t >> 3), q = t & 7;    // 8 k-slabs of 32
        const float* row = emb + (size_t)jj * D + q * 32;
        float v[32];
        float s = 0.f;
        #pragma unroll
        for (int i = 0; i < 8; ++i) {
            const float4 x = *(const float4*)(row + i * 4);
            v[i * 4] = x.x; v[i * 4 + 1] = x.y; v[i * 4 + 2] = x.z; v[i * 4 + 3] = x.w;
            s += x.x * x.x + x.y * x.y + x.z * x.z + x.w * x.w;
        }
        const int g = jj >> 5;
        #pragma unroll
        for (int i = 0; i < 4; ++i) {
            us8 hv;
            #pragma unroll
            for (int c = 0; c < 8; ++c) hv[c] = f2bf(v[i * 8 + c]);
            const int kabs = q * 32 + i * 8;
            const int ks = kabs >> 4;
            const int l = (jj & 31) + ((kabs >> 3) & 1) * 32;
            *(us8*)(Epk + ((size_t)(g * 16 + ks) * 64 + l) * 8) = hv;
        }
        s += __shfl_xor(s, 1);
        s += __shfl_xor(s, 2);
        s += __shfl_xor(s, 4);
        if (q == 0) e2[jj] = s;
    }
}

// ---------------------------------------------------------------------------
// GEMM + group-min + candidate mask. Block: 128 points (LDS, staged once) x
// STRIPS*256 codes. 4 waves; wave wid owns a DISTINCT 64-code column, all 128
// points. Wave frags: 2 code x 4 point of 32x32x16; ef from global (fragment-
// contiguous chunks), pf from LDS; ks+1 register prefetch.
// d~ = e2[code] + acc (Zpk holds -2z). Per (point, 64-code group) emits:
//   tminv[g][pt] = min over 64 codes
//   tmask[g][pt] = bitmask of codes with d~ <= min+MARGIN
// TRANSPOSED [g][pt] layout: lanes c32=0..31 store 32 consecutive pt entries
// -> full-line coalesced stores, no write-allocate round trips.
// ---------------------------------------------------------------------------
__global__ __launch_bounds__(256, 2) void mfma_gemm(
    const unsigned short* __restrict__ Epk, const unsigned short* __restrict__ Zpk,
    const float* __restrict__ e2, float* __restrict__ tminv,
    u64* __restrict__ tmask) {
    __shared__ unsigned short Zbuf[64 * 512];   // 64 KB

    const int tid = threadIdx.x, lane = tid & 63, wid = tid >> 6;
    const int c32 = lane & 31, l5 = lane >> 5;
    const int n0 = blockIdx.x * 128;
    const int cs0 = blockIdx.y * (STRIPS * 256);

    #pragma unroll
    for (int ks = 0; ks < 16; ++ks)
        gl_lds16(Zpk + ((size_t)((n0 >> 5) + wid) * 16 + ks) * 512 + lane * 8,
                 Zbuf + (wid * 16 + ks) * 512);
    __syncthreads();   // single drain per block

    for (int s = 0; s < STRIPS; ++s) {
        const int cb = cs0 + s * 256 + wid * 64;   // this wave's 64 codes
        const unsigned short* eb = Epk + ((size_t)(cb >> 5) * 16) * 512 + lane * 8;
        const unsigned short* zb = Zbuf + lane * 8;

        f32x16 acc[2][4];
        const f32x16 z16 = {0.f};
        #pragma unroll
        for (int i = 0; i < 2; ++i)
            #pragma unroll
            for (int j = 0; j < 4; ++j) acc[i][j] = z16;

        bf16x8 ec[2], pc[4];
        ec[0] = *(const bf16x8*)(eb);
        ec[1] = *(const bf16x8*)(eb + 16 * 512);
        #pragma unroll
        for (int j = 0; j < 4; ++j) pc[j] = *(const bf16x8*)(zb + (j * 16) * 512);

        #pragma unroll 4
        for (int ks = 0; ks < 16; ++ks) {
            bf16x8 en[2], pn[4];
            if (ks < 15) {
                en[0] = *(const bf16x8*)(eb + (ks + 1) * 512);
                en[1] = *(const bf16x8*)(eb + (16 + ks + 1) * 512);
                #pragma unroll
                for (int j = 0; j < 4; ++j)
                    pn[j] = *(const bf16x8*)(zb + (j * 16 + ks + 1) * 512);
            }
            #pragma unroll
            for (int i = 0; i < 2; ++i)
                #pragma unroll
                for (int j = 0; j < 4; ++j)
                    acc[i][j] = __builtin_amdgcn_mfma_f32_32x32x16_bf16(
                        ec[i], pc[j], acc[i][j], 0, 0, 0);
            if (ks < 15) {
                ec[0] = en[0]; ec[1] = en[1];
                #pragma unroll
                for (int j = 0; j < 4; ++j) pc[j] = pn[j];
            }
        }

        // Epilogue: per point-lane, min over the wave's 64 codes + candidate
        // bitmask (codes within MARGIN of the group min).
        float e2r[2][16];
        #pragma unroll
        for (int i = 0; i < 2; ++i)
            #pragma unroll
            for (int r = 0; r < 16; ++r)
                e2r[i][r] = e2[cb + i * 32 + (r & 3) + 8 * (r >> 2) + 4 * l5];
        #pragma unroll
        for (int j = 0; j < 4; ++j) {
            float m = e2r[0][0] + acc[0][j][0];
            #pragma unroll
            for (int r = 1; r < 16; ++r) m = fminf(m, e2r[0][r] + acc[0][j][r]);
            #pragma unroll
            for (int r = 0; r < 16; ++r) m = fminf(m, e2r[1][r] + acc[1][j][r]);
            m = fminf(m, __shfl_xor(m, 32));   // fold the two l5 halves
            const float th = m + MARGIN;
            unsigned mk[2];
            #pragma unroll
            for (int i = 0; i < 2; ++i) {
                unsigned mm = 0;
                #pragma unroll
                for (int r = 0; r < 16; ++r) {
                    const int row = (r & 3) + 8 * (r >> 2) + 4 * l5;
                    mm |= (e2r[i][r] + acc[i][j][r] <= th) ? (1u << row) : 0u;
                }
                mk[i] = mm | (unsigned)__shfl_xor((int)mm, 32);
            }
            if (l5 == 0) {
                const int pt = n0 + j * 32 + c32;
                const int g = cb >> 6;
                tminv[(size_t)g * NPTS + pt] = m;                       // 128B line
                tmask[(size_t)g * NPTS + pt] =
                    ((u64)mk[1] << 32) | (u64)mk[0];                    // 256B run
            }
        }
    }
}

// ---------------------------------------------------------------------------
// Rescore: m1 = min over 256 group-mins; for groups with gmin <= m1 + MARGIN,
// read the candidate bitmask and exact-fp32 rescore ONLY those codes, each as
// one coalesced 1KB row load + butterfly dot-reduce. Tie -> lowest j.
// tminv is [g][pt]: block stages its 4 points' 256 group-mins through LDS
// (thread t loads float4 tminv[t][n0..n0+3]; padded stride-5 for banks).
// tmask reads are wave-uniform scalars. Emits idxf + total_idx. Zeroes loss.
// ---------------------------------------------------------------------------
__global__ __launch_bounds__(256) void rescore(
    const float* __restrict__ tminv, const u64* __restrict__ tmask,
    const float* __restrict__ Zf32, const float* __restrict__ emb,
    const float* __restrict__ e2, int* __restrict__ idxf,
    float* __restrict__ out_idx, float* __restrict__ loss) {
    __shared__ float sm[256 * 5];   // [g][4 pts], stride 5 (bank-spread)
    const int tid = threadIdx.x, lane = tid & 63, w = tid >> 6;
    const int n0 = blockIdx.x * 4;
    const int n = n0 + w;
    if (blockIdx.x == 0 && tid == 0) loss[0] = 0.f;

    {   // stage tminv[g][n0..n0+3] for g = tid
        const float4 v = *(const float4*)(tminv + (size_t)tid * NPTS + n0);
        sm[tid * 5 + 0] = v.x; sm[tid * 5 + 1] = v.y;
        sm[tid * 5 + 2] = v.z; sm[tid * 5 + 3] = v.w;
    }
    const float4 zr = *(const float4*)(Zf32 + (size_t)n * D + lane * 4);
    __syncthreads();

    float tva[4];
    #pragma unroll
    for (int k = 0; k < 4; ++k) tva[k] = sm[(k * 64 + lane) * 5 + w];
    float m1 = fminf(fminf(tva[0], tva[1]), fminf(tva[2], tva[3]));
    #pragma unroll
    for (int st = 1; st < 64; st <<= 1) m1 = fminf(m1, __shfl_xor(m1, st));
    const float thresh = m1 + MARGIN;

    u64 best = ~0ull;
    #pragma unroll
    for (int k = 0; k < 4; ++k) {
        u64 gm = __ballot(tva[k] <= thresh);
        while (gm) {
            const int bit = (int)__builtin_ctzll(gm);
            gm &= gm - 1;
            const int g = k * 64 + bit;                // 64-code group id
            u64 cm = tmask[(size_t)g * NPTS + n];      // uniform broadcast
            while (cm) {
                const int r = (int)__builtin_ctzll(cm);
                cm &= cm - 1;
                const int c = g * 64 + r;
                const float4 ev = *(const float4*)(emb + (size_t)c * D + lane * 4);
                float s = zr.x * ev.x + zr.y * ev.y + zr.z * ev.z + zr.w * ev.w;
                #pragma unroll
                for (int st = 1; st < 64; st <<= 1) s += __shfl_xor(s, st);
                const float d = e2[c] - 2.0f * s;
                unsigned int u = __float_as_uint(d);
                u = (u & 0x80000000u) ? ~u : (u | 0x80000000u);
                const u64 key = ((u64)u << 32) | (unsigned int)c;
                if (key < best) best = key;            // same on all lanes
            }
        }
    }
    if (lane == 0) {
        const int bi = (int)(unsigned int)(best & 0xFFFFFFFFull);
        idxf[n] = bi;
        const int b = n >> 10, hw = n & 1023;
        const float fv = (float)bi;
        #pragma unroll
        for (int sc = 0; sc < 4; ++sc) out_idx[b * 4096 + sc * 1024 + hw] = fv;
    }
}

// ---------------------------------------------------------------------------
// Gather q = emb[idx]; z_hat_out = z + (4q - z); loss accumulation.
// 1024 blocks: (4 c-tiles of 64) x (8 b x 32 hw-tiles). 256 thr = 32 hw x 8 cg.
// ---------------------------------------------------------------------------
__global__ __launch_bounds__(256) void quant_loss(
    const float* __restrict__ z, const float* __restrict__ emb,
    const int* __restrict__ idxf, float* __restrict__ out,
    float* __restrict__ loss) {
    __shared__ int idx_l[32];
    __shared__ float wsum[4];
    const int blk = blockIdx.x;
    const int c0 = (blk >> 8) * 64;
    const int rem = blk & 255;
    const int b = rem >> 5, hw0 = (rem & 31) * 32;
    const int t = threadIdx.x, hw_l = t & 31, cg = t >> 5;
    if (t < 32) idx_l[t] = idxf[b * 1024 + hw0 + t];
    __syncthreads();
    const int j = idx_l[hw_l];
    const float* er = emb + (size_t)j * D + c0 + cg * 8;
    const float4 q0 = *(const float4*)er;
    const float4 q1 = *(const float4*)(er + 4);
    const float qv[8] = {q0.x, q0.y, q0.z, q0.w, q1.x, q1.y, q1.z, q1.w};
    float e = 0.f;
    #pragma unroll
    for (int cc = 0; cc < 8; ++cc) {
        const int c = c0 + cg * 8 + cc;
        const size_t zi = (size_t)b * 262144 + (size_t)c * 1024 + hw0 + hw_l;
        const float zv = z[zi];
        const float q = qv[cc];
        const float zh = ((q + q) + q) + q;   // mimic 4-step accumulation
        out[zi] = zv + (zh - zv);
        e += 30.0f * q * q - 20.0f * q * zv + 4.0f * zv * zv;
    }
    #pragma unroll
    for (int off = 32; off > 0; off >>= 1) e += __shfl_down(e, off);
    if ((t & 63) == 0) wsum[t >> 6] = e;
    __syncthreads();
    if (t == 0) {
        const float s = wsum[0] + wsum[1] + wsum[2] + wsum[3];
        atomicAdd(loss, s * (0.3125f / 2097152.0f));
    }
}

// ---------------------------------------------------------------------------
extern "C" void kernel_launch(void* const* d_in, const int* in_sizes, int n_in,
                              void* d_out, int out_size, void* d_ws, size_t ws_size,
                              hipStream_t stream) {
    const float* z = (const float*)d_in[0];     // [8,256,32,32]
    const float* emb = (const float*)d_in[1];   // [16384,256]
    float* out = (float*)d_out;                 // z_hat_out | loss | total_idx

    // Workspace (~46.3 MB)
    unsigned short* Zpk = (unsigned short*)d_ws;            // 8192*256 bf16
    unsigned short* Epk = Zpk + (size_t)NPTS * D;           // 16384*256 bf16
    float* Zf32 = (float*)(Epk + (size_t)N_E * D);          // 8192*256 f32
    float* e2 = Zf32 + (size_t)NPTS * D;                    // 16384 f32
    float* tminv = e2 + N_E;                                // 256*8192 f32 [g][pt]
    u64* tmask = (u64*)(tminv + (size_t)NPTS * 256);        // 256*8192 u64 [g][pt]
    int* idxf = (int*)(tmask + (size_t)NPTS * 256);         // 8192 i32

    float* loss = out + ZOUT;
    float* out_idx = out + ZOUT + 1;

    prep<<<768, 256, 0, stream>>>(z, emb, Zpk, Zf32, Epk, e2);
    mfma_gemm<<<dim3(NPTS / 128, N_E / (256 * STRIPS)), 256, 0, stream>>>(
        Epk, Zpk, e2, tminv, tmask);
    rescore<<<NPTS / 4, 256, 0, stream>>>(tminv, tmask, Zf32, emb, e2, idxf,
                                          out_idx, loss);
    quant_loss<<<1024, 256, 0, stream>>>(z, emb, idxf, out, loss);
}